// Round 1
// baseline (1955.309 us; speedup 1.0000x reference)
//
#include <hip/hip_runtime.h>
#include <stdint.h>

#define SEQ   2048
#define NBATCH 64
#define IND   256
#define HIDN  256

using short8  = __attribute__((ext_vector_type(8))) short;
using floatx4 = __attribute__((ext_vector_type(4))) float;
using us4     = __attribute__((ext_vector_type(4))) unsigned short;
using uintx2  = __attribute__((ext_vector_type(2))) unsigned;

__device__ __forceinline__ unsigned bf16r(float f) {
    unsigned u = __builtin_bit_cast(unsigned, f);
    return (u + 0x8000u) >> 16;   // round-half-up to bf16
}

__device__ __forceinline__ short8 pack8(floatx4 f0, floatx4 f1) {
    short8 s;
    s[0] = (short)bf16r(f0[0]); s[1] = (short)bf16r(f0[1]);
    s[2] = (short)bf16r(f0[2]); s[3] = (short)bf16r(f0[3]);
    s[4] = (short)bf16r(f1[0]); s[5] = (short)bf16r(f1[1]);
    s[6] = (short)bf16r(f1[2]); s[7] = (short)bf16r(f1[3]);
    return s;
}

// tanh(z) = 1 - 2/(1+e^{2z});  e^{2z} = exp2(z * 2/ln2).  NaN-safe at +-inf.
__device__ __forceinline__ float tanh_fast(float z) {
    float a = __builtin_amdgcn_exp2f(z * 2.8853900817779268f);
    return __builtin_fmaf(-2.0f, __builtin_amdgcn_rcpf(1.0f + a), 1.0f);
}

// pack 2 fp32 -> 2 bf16 in one VALU op (RNE). No builtin on gfx950 (m240);
// inline asm per T12 recipe.
__device__ __forceinline__ unsigned cvt_pk_bf16(float lo, float hi) {
    unsigned r;
    asm("v_cvt_pk_bf16_f32 %0, %1, %2" : "=v"(r) : "v"(lo), "v"(hi));
    return r;
}

// LDS-only barrier: s_waitcnt lgkmcnt(0) + s_barrier. 0xc07f = vmcnt(63)
// expcnt(7) lgkmcnt(0). Keeps global stores / xp prefetch in flight.
__device__ __forceinline__ void lds_barrier() {
    __builtin_amdgcn_s_waitcnt(0xc07f);
    __builtin_amdgcn_s_barrier();
}

// ---------------------------------------------------------------------------
// Kernel 1: x_proj[s][b][n] = input[s][b][:] . W_ih[n][:] + b_ih[n] + b_hh[n]
// stored as bf16 bits. Grid: 2048 blocks x 256 thr; 64 M-rows/block.
// (unchanged this round -- isolating the rnn operand-swap restructure)
// ---------------------------------------------------------------------------
__global__ __launch_bounds__(256, 2) void proj_kernel(
    const float* __restrict__ inp, const float* __restrict__ W_ih,
    const float* __restrict__ b_ih, const float* __restrict__ b_hh,
    unsigned short* __restrict__ xp)
{
    const int tid  = threadIdx.x;
    const int w    = tid >> 6;
    const int lane = tid & 63;
    const int c    = lane & 15;
    const int q    = lane >> 4;
    const size_t R0 = (size_t)blockIdx.x * 64;

    short8 bfr[4][8];
    float bias[4];
    #pragma unroll
    for (int tn = 0; tn < 4; ++tn) {
        const int n = 64 * w + 16 * tn + c;
        bias[tn] = b_ih[n] + b_hh[n];
        #pragma unroll
        for (int kk = 0; kk < 8; ++kk) {
            const float* p = W_ih + (size_t)n * 256 + kk * 32 + q * 8;
            bfr[tn][kk] = pack8(*(const floatx4*)p, *(const floatx4*)(p + 4));
        }
    }

    #pragma unroll
    for (int mt = 0; mt < 4; ++mt) {
        short8 afr[8];
        const float* arow = inp + (R0 + 16 * mt + c) * 256;
        #pragma unroll
        for (int kk = 0; kk < 8; ++kk) {
            const float* p = arow + kk * 32 + q * 8;
            afr[kk] = pack8(*(const floatx4*)p, *(const floatx4*)(p + 4));
        }
        floatx4 acc[4];
        #pragma unroll
        for (int tn = 0; tn < 4; ++tn) {
            floatx4 a0; a0[0] = bias[tn]; a0[1] = bias[tn]; a0[2] = bias[tn]; a0[3] = bias[tn];
            acc[tn] = a0;
        }
        #pragma unroll
        for (int kk = 0; kk < 8; ++kk)
            #pragma unroll
            for (int tn = 0; tn < 4; ++tn)
                acc[tn] = __builtin_amdgcn_mfma_f32_16x16x32_bf16(afr[kk], bfr[tn][kk], acc[tn], 0, 0, 0);
        #pragma unroll
        for (int tn = 0; tn < 4; ++tn) {
            const unsigned col = 64 * w + 16 * tn + c;
            #pragma unroll
            for (int r = 0; r < 4; ++r) {
                const size_t row = R0 + 16 * mt + q * 4 + r;
                xp[row * 256 + col] = (unsigned short)bf16r(acc[tn][r]);
            }
        }
    }
}

// ---------------------------------------------------------------------------
// Kernel 2: serial recurrence, SWAPPED-OPERAND form. 4 blocks x 16 batches,
// 8 waves/block. We compute D' = W_hh . h^T (= (h.W_hh^T)^T): W as the MFMA
// A operand (static regs, bit-identical to the old B-frag load), h as the B
// operand (same hbuf b128 read as the old A-frag read). The C-frag now holds
// 4 CONSECUTIVE hid elements of ONE batch row per lane (row=hid=32w+16t2+4q+r,
// col=batch=c), so:
//   h LDS write:  8x ds_write_u16  -> 2x ds_write_b64 (cvt_pk_bf16 packed)
//   out store:    8x store_dword   -> 2x store_dwordx4
//   xp prefetch:  8x ushort loads  -> 2x ushort4 loads
// W_hh slice in registers; h double-buffered in LDS bf16, stride 264 ushort
// (same conflict-minimal b128 read pattern as before).
// ---------------------------------------------------------------------------
__global__ __launch_bounds__(512, 2) void rnn_kernel(
    const float* __restrict__ W_hh,
    const unsigned short* __restrict__ xp,   // bf16 bits [SEQ][NBATCH][HIDN]
    float* __restrict__ out)                 // fp32 [SEQ*NBATCH][HIDN]
{
    __shared__ __align__(16) unsigned short hbuf[2][16 * 264];
    const int tid  = threadIdx.x;
    const int w    = tid >> 6, lane = tid & 63;   // w in [0,8)
    const int c    = lane & 15, q = lane >> 4;
    const int B0   = blockIdx.x * 16;

    // A-frags (W rows) for this wave's 32 output rows: m = 32w + 16*t2 + c.
    // Identical register contents to the previous kernel's B-frags.
    short8 wfr[2][8];
    #pragma unroll
    for (int t2 = 0; t2 < 2; ++t2) {
        const int n = 32 * w + 16 * t2 + c;
        #pragma unroll
        for (int kk = 0; kk < 8; ++kk) {
            const float* p = W_hh + (size_t)n * 256 + kk * 32 + q * 8;
            wfr[t2][kk] = pack8(*(const floatx4*)p, *(const floatx4*)(p + 4));
        }
    }

    // h0 = 0
    for (int i = tid; i < 2 * 16 * 264; i += 512) (&hbuf[0][0])[i] = 0;
    __syncthreads();

    // per-lane flat offset into [t][b][n]: b = B0+c, n = 32w + 16*t2 + 4q + r
    const unsigned lofs = (unsigned)(B0 + c) * 256 + 32 * w + 4 * q;
    const unsigned short* xq = xp + lofs;
    float* oq = out + lofs;
    // LDS write base: hbuf[.][batch=c][hid = 32w + 16*t2 + 4q + r]
    const unsigned wofs = (unsigned)c * 264 + 32 * w + 4 * q;

    // 2-deep xp prefetch ring; one ushort4 per chain t2
    us4 xa[2], xb[2];
    #pragma unroll
    for (int t2 = 0; t2 < 2; ++t2) {
        xa[t2] = *(const us4*)(xq + 16 * t2);
        xb[t2] = *(const us4*)(xq + 16384 + 16 * t2);
    }

    auto step = [&](int t, int sel, us4* xv) {
        // B-frags first (only dep: barrier) so LDS latency overlaps VALU below.
        // Same read pattern as the old A-frag read: h[batch=c][k].
        short8 hfr[8];
        #pragma unroll
        for (int kk = 0; kk < 8; ++kk)
            hfr[kk] = *(const short8*)&hbuf[sel][c * 264 + kk * 32 + q * 8];

        // acc init = x_proj (prefetched 2 steps ago; bf16 -> f32 is <<16)
        floatx4 acc[2];
        #pragma unroll
        for (int t2 = 0; t2 < 2; ++t2) {
            floatx4 a0;
            a0[0] = __builtin_bit_cast(float, (unsigned)xv[t2][0] << 16);
            a0[1] = __builtin_bit_cast(float, (unsigned)xv[t2][1] << 16);
            a0[2] = __builtin_bit_cast(float, (unsigned)xv[t2][2] << 16);
            a0[3] = __builtin_bit_cast(float, (unsigned)xv[t2][3] << 16);
            acc[t2] = a0;
        }

        // prefetch x_proj for t+2 (clamped; dead-but-in-bounds at the tail)
        {
            const int tp = (t + 2 < SEQ) ? (t + 2) : (SEQ - 1);
            const unsigned short* p = xq + (size_t)tp * 16384;
            xv[0] = *(const us4*)(p);
            xv[1] = *(const us4*)(p + 16);
        }

        // kk-outer: 2 interleaved chains; second wave on the SIMD fills gaps.
        // W is arg0 (A), h is arg1 (B): D' = W.h^T = old-D transposed.
        #pragma unroll
        for (int kk = 0; kk < 8; ++kk)
            #pragma unroll
            for (int t2 = 0; t2 < 2; ++t2)
                acc[t2] = __builtin_amdgcn_mfma_f32_16x16x32_bf16(wfr[t2][kk], hfr[kk], acc[t2], 0, 0, 0);

        // epilogue: tanh, fp32 out store (dwordx4), bf16 h_new (ds_write_b64)
        float* op = oq + (size_t)t * 16384;
        unsigned short* hw = &hbuf[sel ^ 1][0];
        #pragma unroll
        for (int t2 = 0; t2 < 2; ++t2) {
            const float h0 = tanh_fast(acc[t2][0]);
            const float h1 = tanh_fast(acc[t2][1]);
            const float h2 = tanh_fast(acc[t2][2]);
            const float h3 = tanh_fast(acc[t2][3]);
            floatx4 o; o[0] = h0; o[1] = h1; o[2] = h2; o[3] = h3;
            *reinterpret_cast<floatx4*>(op + 16 * t2) = o;
            uintx2 hv;
            hv[0] = cvt_pk_bf16(h0, h1);
            hv[1] = cvt_pk_bf16(h2, h3);
            *reinterpret_cast<uintx2*>(hw + wofs + 16 * t2) = hv;
        }
        lds_barrier();
    };

    for (int t = 0; t < SEQ; t += 2) {
        step(t, 0, xa);
        step(t + 1, 1, xb);
    }
}

extern "C" void kernel_launch(void* const* d_in, const int* in_sizes, int n_in,
                              void* d_out, int out_size, void* d_ws, size_t ws_size,
                              hipStream_t stream) {
    const float* input = (const float*)d_in[0];
    const float* W_ih  = (const float*)d_in[1];
    const float* W_hh  = (const float*)d_in[2];
    const float* b_ih  = (const float*)d_in[3];
    const float* b_hh  = (const float*)d_in[4];
    float* out = (float*)d_out;
    unsigned short* xp = (unsigned short*)d_ws;  // 2048*64*256 bf16 = 64 MiB

    proj_kernel<<<(SEQ * NBATCH) / 64, 256, 0, stream>>>(input, W_ih, b_ih, b_hh, xp);
    rnn_kernel<<<4, 512, 0, stream>>>(W_hh, xp, out);
}

// Round 2
// 1609.517 us; speedup vs baseline: 1.2148x; 1.2148x over previous
//
#include <hip/hip_runtime.h>
#include <stdint.h>

#define SEQ   2048
#define NBATCH 64
#define IND   256
#define HIDN  256

using short8  = __attribute__((ext_vector_type(8))) short;
using floatx4 = __attribute__((ext_vector_type(4))) float;

__device__ __forceinline__ unsigned bf16r(float f) {
    unsigned u = __builtin_bit_cast(unsigned, f);
    return (u + 0x8000u) >> 16;   // round-half-up to bf16
}

// legacy pack (round-half-up) -- used by rnn_kernel W load for bit-exact revert
__device__ __forceinline__ short8 pack8(floatx4 f0, floatx4 f1) {
    short8 s;
    s[0] = (short)bf16r(f0[0]); s[1] = (short)bf16r(f0[1]);
    s[2] = (short)bf16r(f0[2]); s[3] = (short)bf16r(f0[3]);
    s[4] = (short)bf16r(f1[0]); s[5] = (short)bf16r(f1[1]);
    s[6] = (short)bf16r(f1[2]); s[7] = (short)bf16r(f1[3]);
    return s;
}

// pack 2 fp32 -> 2 bf16 in one VALU op (RNE). No builtin on gfx950; T12 recipe.
__device__ __forceinline__ unsigned cvt_pk_bf16(float lo, float hi) {
    unsigned r;
    asm("v_cvt_pk_bf16_f32 %0, %1, %2" : "=v"(r) : "v"(lo), "v"(hi));
    return r;
}

// fast pack: 4 VALU ops instead of ~20 (proj_kernel only)
__device__ __forceinline__ short8 pack8_pk(floatx4 f0, floatx4 f1) {
    union { unsigned u[4]; short8 s; } r;
    r.u[0] = cvt_pk_bf16(f0[0], f0[1]);
    r.u[1] = cvt_pk_bf16(f0[2], f0[3]);
    r.u[2] = cvt_pk_bf16(f1[0], f1[1]);
    r.u[3] = cvt_pk_bf16(f1[2], f1[3]);
    return r.s;
}

// tanh(z) = 1 - 2/(1+e^{2z});  e^{2z} = exp2(z * 2/ln2).  NaN-safe at +-inf.
__device__ __forceinline__ float tanh_fast(float z) {
    float a = __builtin_amdgcn_exp2f(z * 2.8853900817779268f);
    return __builtin_fmaf(-2.0f, __builtin_amdgcn_rcpf(1.0f + a), 1.0f);
}

// LDS-only barrier: s_waitcnt lgkmcnt(0) + s_barrier. 0xc07f = vmcnt(63)
// expcnt(7) lgkmcnt(0). Keeps global stores / xp prefetch in flight.
__device__ __forceinline__ void lds_barrier() {
    __builtin_amdgcn_s_waitcnt(0xc07f);
    __builtin_amdgcn_s_barrier();
}

// ---------------------------------------------------------------------------
// Kernel 1: x_proj[s][b][n] = input[s][b][:] . W_ih[n][:] + b_ih[n] + b_hh[n]
// stored as bf16 bits. Grid: 2048 blocks x 256 thr; 64 M-rows/block.
// v2: input tile staged in LDS as bf16 ONCE per block (coalesced float4
// loads + cvt_pk pack), shared by all 4 waves -- removes the 4x-redundant
// 16-row-scattered global frag loads and 4x of the repack VALU. A-frag read
// uses the 264-ushort-stride pattern proven conflict-minimal in rnn's hbuf.
// W path + MFMA + store epilogue unchanged from the verified version
// (W pack switched to cvt_pk: RNE vs half-up, <=1ulp on weights).
// ---------------------------------------------------------------------------
__global__ __launch_bounds__(256, 2) void proj_kernel(
    const float* __restrict__ inp, const float* __restrict__ W_ih,
    const float* __restrict__ b_ih, const float* __restrict__ b_hh,
    unsigned short* __restrict__ xp)
{
    __shared__ __align__(16) unsigned short abuf[64 * 264];   // 33.8 KB
    const int tid  = threadIdx.x;
    const int w    = tid >> 6;
    const int lane = tid & 63;
    const int c    = lane & 15;
    const int q    = lane >> 4;
    const size_t R0 = (size_t)blockIdx.x * 64;

    // cooperative stage: 64 rows x 256 fp32 -> bf16 LDS [64][264].
    // thread handles 8 consecutive floats per phase; fully coalesced loads,
    // stride-1 b128 LDS writes (conflict-free).
    {
        const float* src = inp + R0 * 256;
        #pragma unroll
        for (int ph = 0; ph < 8; ++ph) {
            const int e = ph * 2048 + tid * 8;
            floatx4 f0 = *(const floatx4*)(src + e);
            floatx4 f1 = *(const floatx4*)(src + e + 4);
            const int r = e >> 8, col = e & 255;
            *(short8*)&abuf[r * 264 + col] = pack8_pk(f0, f1);
        }
    }

    // W frags + bias (global latency hides under the stage + barrier)
    short8 bfr[4][8];
    float bias[4];
    #pragma unroll
    for (int tn = 0; tn < 4; ++tn) {
        const int n = 64 * w + 16 * tn + c;
        bias[tn] = b_ih[n] + b_hh[n];
        #pragma unroll
        for (int kk = 0; kk < 8; ++kk) {
            const float* p = W_ih + (size_t)n * 256 + kk * 32 + q * 8;
            bfr[tn][kk] = pack8_pk(*(const floatx4*)p, *(const floatx4*)(p + 4));
        }
    }

    __syncthreads();

    #pragma unroll
    for (int mt = 0; mt < 4; ++mt) {
        short8 afr[8];
        #pragma unroll
        for (int kk = 0; kk < 8; ++kk)
            afr[kk] = *(const short8*)&abuf[(16 * mt + c) * 264 + kk * 32 + q * 8];
        floatx4 acc[4];
        #pragma unroll
        for (int tn = 0; tn < 4; ++tn) {
            floatx4 a0; a0[0] = bias[tn]; a0[1] = bias[tn]; a0[2] = bias[tn]; a0[3] = bias[tn];
            acc[tn] = a0;
        }
        #pragma unroll
        for (int kk = 0; kk < 8; ++kk)
            #pragma unroll
            for (int tn = 0; tn < 4; ++tn)
                acc[tn] = __builtin_amdgcn_mfma_f32_16x16x32_bf16(afr[kk], bfr[tn][kk], acc[tn], 0, 0, 0);
        #pragma unroll
        for (int tn = 0; tn < 4; ++tn) {
            const unsigned col = 64 * w + 16 * tn + c;
            #pragma unroll
            for (int r = 0; r < 4; ++r) {
                const size_t row = R0 + 16 * mt + q * 4 + r;
                xp[row * 256 + col] = (unsigned short)bf16r(acc[tn][r]);
            }
        }
    }
}

// ---------------------------------------------------------------------------
// Kernel 2: serial recurrence. 4 blocks x 16 batches, 8 WAVES/block
// (2 waves/SIMD): wave w owns a 32-wide hidden slice (2 MFMA chains).
// EXACT revert to the 1360us round-0 version: the operand-swap variant
// regressed 22% (emergent 2-wave stagger loss); do not touch the step
// structure without a stagger mechanism.
// ---------------------------------------------------------------------------
__global__ __launch_bounds__(512, 2) void rnn_kernel(
    const float* __restrict__ W_hh,
    const unsigned short* __restrict__ xp,   // bf16 bits [SEQ][NBATCH][HIDN]
    float* __restrict__ out)                 // fp32 [SEQ*NBATCH][HIDN]
{
    __shared__ __align__(16) unsigned short hbuf[2][16 * 264];
    const int tid  = threadIdx.x;
    const int w    = tid >> 6, lane = tid & 63;   // w in [0,8)
    const int c    = lane & 15, q = lane >> 4;
    const int B0   = blockIdx.x * 16;

    // B-frags for this wave's 32 columns: n = 32w + 16*t2 + c, t2 in {0,1}
    short8 bfr[2][8];
    #pragma unroll
    for (int t2 = 0; t2 < 2; ++t2) {
        const int n = 32 * w + 16 * t2 + c;
        #pragma unroll
        for (int kk = 0; kk < 8; ++kk) {
            const float* p = W_hh + (size_t)n * 256 + kk * 32 + q * 8;
            bfr[t2][kk] = pack8(*(const floatx4*)p, *(const floatx4*)(p + 4));
        }
    }

    // h0 = 0
    for (int i = tid; i < 2 * 16 * 264; i += 512) (&hbuf[0][0])[i] = 0;
    __syncthreads();

    // per-lane flat offset into [t][b][n]: b = B0+q*4+r, n = 32w+16*t2+c
    const unsigned lofs = (unsigned)(B0 + q * 4) * 256 + 32 * w + c;
    const unsigned short* xq = xp + lofs;
    float* oq = out + lofs;

    // 2-deep xp prefetch ring; i = r*2 + t2
    unsigned xa[8], xb[8];
    #pragma unroll
    for (int i = 0; i < 8; ++i) {
        const int t2 = i & 1, r = i >> 1;
        xa[i] = xq[r * 256 + t2 * 16];
        xb[i] = xq[16384 + r * 256 + t2 * 16];
    }

    auto step = [&](int t, int sel, unsigned* xv) {
        // A-frags first (only dep: barrier) so LDS latency overlaps VALU below
        short8 afr[8];
        #pragma unroll
        for (int kk = 0; kk < 8; ++kk)
            afr[kk] = *(const short8*)&hbuf[sel][c * 264 + kk * 32 + q * 8];

        // acc init = x_proj (prefetched 2 steps ago; bf16 -> f32 is <<16)
        floatx4 acc[2];
        #pragma unroll
        for (int t2 = 0; t2 < 2; ++t2) {
            floatx4 a0;
            a0[0] = __builtin_bit_cast(float, xv[0 * 2 + t2] << 16);
            a0[1] = __builtin_bit_cast(float, xv[1 * 2 + t2] << 16);
            a0[2] = __builtin_bit_cast(float, xv[2 * 2 + t2] << 16);
            a0[3] = __builtin_bit_cast(float, xv[3 * 2 + t2] << 16);
            acc[t2] = a0;
        }

        // prefetch x_proj for t+2 (clamped; dead-but-in-bounds at the tail)
        {
            const int tp = (t + 2 < SEQ) ? (t + 2) : (SEQ - 1);
            const unsigned short* p = xq + (size_t)tp * 16384;
            #pragma unroll
            for (int i = 0; i < 8; ++i) {
                const int t2 = i & 1, r = i >> 1;
                xv[i] = p[r * 256 + t2 * 16];
            }
        }

        // kk-outer: 2 interleaved chains; second wave on the SIMD fills gaps
        #pragma unroll
        for (int kk = 0; kk < 8; ++kk)
            #pragma unroll
            for (int t2 = 0; t2 < 2; ++t2)
                acc[t2] = __builtin_amdgcn_mfma_f32_16x16x32_bf16(afr[kk], bfr[t2][kk], acc[t2], 0, 0, 0);

        // epilogue: tanh, fp32 out store, bf16 h_new into other LDS buffer
        float* op = oq + (size_t)t * 16384;
        unsigned short* hw = &hbuf[sel ^ 1][0];
        #pragma unroll
        for (int t2 = 0; t2 < 2; ++t2) {
            #pragma unroll
            for (int r = 0; r < 4; ++r) {
                const float hn = tanh_fast(acc[t2][r]);
                op[r * 256 + t2 * 16] = hn;
                hw[(q * 4 + r) * 264 + 32 * w + 16 * t2 + c] = (unsigned short)bf16r(hn);
            }
        }
        lds_barrier();
    };

    for (int t = 0; t < SEQ; t += 2) {
        step(t, 0, xa);
        step(t + 1, 1, xb);
    }
}

extern "C" void kernel_launch(void* const* d_in, const int* in_sizes, int n_in,
                              void* d_out, int out_size, void* d_ws, size_t ws_size,
                              hipStream_t stream) {
    const float* input = (const float*)d_in[0];
    const float* W_ih  = (const float*)d_in[1];
    const float* W_hh  = (const float*)d_in[2];
    const float* b_ih  = (const float*)d_in[3];
    const float* b_hh  = (const float*)d_in[4];
    float* out = (float*)d_out;
    unsigned short* xp = (unsigned short*)d_ws;  // 2048*64*256 bf16 = 64 MiB

    proj_kernel<<<(SEQ * NBATCH) / 64, 256, 0, stream>>>(input, W_ih, b_ih, b_hh, xp);
    rnn_kernel<<<4, 512, 0, stream>>>(W_hh, xp, out);
}

// Round 4
// 1585.403 us; speedup vs baseline: 1.2333x; 1.0152x over previous
//
#include <hip/hip_runtime.h>
#include <stdint.h>

#define SEQ   2048
#define NBATCH 64
#define IND   256
#define HIDN  256

using short8  = __attribute__((ext_vector_type(8))) short;
using floatx4 = __attribute__((ext_vector_type(4))) float;

__device__ __forceinline__ unsigned bf16r(float f) {
    unsigned u = __builtin_bit_cast(unsigned, f);
    return (u + 0x8000u) >> 16;   // round-half-up to bf16
}

// legacy pack (round-half-up) -- used by rnn_kernel W load for bit-exact keep
__device__ __forceinline__ short8 pack8(floatx4 f0, floatx4 f1) {
    short8 s;
    s[0] = (short)bf16r(f0[0]); s[1] = (short)bf16r(f0[1]);
    s[2] = (short)bf16r(f0[2]); s[3] = (short)bf16r(f0[3]);
    s[4] = (short)bf16r(f1[0]); s[5] = (short)bf16r(f1[1]);
    s[6] = (short)bf16r(f1[2]); s[7] = (short)bf16r(f1[3]);
    return s;
}

// pack 2 fp32 -> 2 bf16 in one VALU op (RNE). No builtin on gfx950; T12 recipe.
__device__ __forceinline__ unsigned cvt_pk_bf16(float lo, float hi) {
    unsigned r;
    asm("v_cvt_pk_bf16_f32 %0, %1, %2" : "=v"(r) : "v"(lo), "v"(hi));
    return r;
}

// fast pack: 4 VALU ops instead of ~20 (proj_kernel only)
__device__ __forceinline__ short8 pack8_pk(floatx4 f0, floatx4 f1) {
    union { unsigned u[4]; short8 s; } r;
    r.u[0] = cvt_pk_bf16(f0[0], f0[1]);
    r.u[1] = cvt_pk_bf16(f0[2], f0[3]);
    r.u[2] = cvt_pk_bf16(f1[0], f1[1]);
    r.u[3] = cvt_pk_bf16(f1[2], f1[3]);
    return r.s;
}

// tanh(z) = 1 - 2/(1+e^{2z});  e^{2z} = exp2(z * 2/ln2).  NaN-safe at +-inf.
__device__ __forceinline__ float tanh_fast(float z) {
    float a = __builtin_amdgcn_exp2f(z * 2.8853900817779268f);
    return __builtin_fmaf(-2.0f, __builtin_amdgcn_rcpf(1.0f + a), 1.0f);
}

// LDS-only barrier: s_waitcnt lgkmcnt(0) + s_barrier. 0xc07f = vmcnt(63)
// expcnt(7) lgkmcnt(0). Keeps global stores / prefetch loads in flight.
__device__ __forceinline__ void lds_barrier() {
    __builtin_amdgcn_s_waitcnt(0xc07f);
    __builtin_amdgcn_s_barrier();
}

// ---------------------------------------------------------------------------
// Kernel 1 v4: x_proj = input . W_ih^T + b, stored bf16 as [row][hid].
// EXACTLY round-2's verified v2 math (same stage pack, same W pack, same
// MFMA operand order, same scalar bf16r stores -- bit-identical output),
// with ONE change: grid 2048 -> 512 blocks; each block loops over 4
// consecutive 64-row tiles, keeping its packed W frags in registers.
// W_ih L2 traffic + pack VALU drop 4x. Single LDS buffer, two extra
// lds_barriers per tile (reads-done / writes-visible).
// The round-3 bundled rewrite (operand swap + dbuf + vec stores) NaN'd;
// one structural change per round from here on.
// ---------------------------------------------------------------------------
__global__ __launch_bounds__(256, 2) void proj_kernel(
    const float* __restrict__ inp, const float* __restrict__ W_ih,
    const float* __restrict__ b_ih, const float* __restrict__ b_hh,
    unsigned short* __restrict__ xp)
{
    __shared__ __align__(16) unsigned short abuf[64 * 264];   // 33.8 KB
    const int tid  = threadIdx.x;
    const int w    = tid >> 6;
    const int lane = tid & 63;
    const int c    = lane & 15;
    const int q    = lane >> 4;
    const size_t R0 = (size_t)blockIdx.x * 256;   // 4 tiles x 64 rows

    // stage tile 0 (verbatim v2 stage: coalesced float4 loads, cvt_pk pack,
    // stride-1 b128 LDS writes)
    {
        const float* src = inp + R0 * 256;
        #pragma unroll
        for (int ph = 0; ph < 8; ++ph) {
            const int e = ph * 2048 + tid * 8;
            floatx4 f0 = *(const floatx4*)(src + e);
            floatx4 f1 = *(const floatx4*)(src + e + 4);
            *(short8*)&abuf[(e >> 8) * 264 + (e & 255)] = pack8_pk(f0, f1);
        }
    }

    // W frags + bias, packed ONCE per block (global latency hides under the
    // tile-0 stage). Verbatim v2.
    short8 bfr[4][8];
    float bias[4];
    #pragma unroll
    for (int tn = 0; tn < 4; ++tn) {
        const int n = 64 * w + 16 * tn + c;
        bias[tn] = b_ih[n] + b_hh[n];
        #pragma unroll
        for (int kk = 0; kk < 8; ++kk) {
            const float* p = W_ih + (size_t)n * 256 + kk * 32 + q * 8;
            bfr[tn][kk] = pack8_pk(*(const floatx4*)p, *(const floatx4*)(p + 4));
        }
    }

    __syncthreads();

    for (int j = 0; j < 4; ++j) {
        const size_t Rj = R0 + (size_t)j * 64;

        // compute tile j (verbatim v2 mt-loop)
        #pragma unroll
        for (int mt = 0; mt < 4; ++mt) {
            short8 afr[8];
            #pragma unroll
            for (int kk = 0; kk < 8; ++kk)
                afr[kk] = *(const short8*)&abuf[(16 * mt + c) * 264 + kk * 32 + q * 8];
            floatx4 acc[4];
            #pragma unroll
            for (int tn = 0; tn < 4; ++tn) {
                floatx4 a0; a0[0] = bias[tn]; a0[1] = bias[tn]; a0[2] = bias[tn]; a0[3] = bias[tn];
                acc[tn] = a0;
            }
            #pragma unroll
            for (int kk = 0; kk < 8; ++kk)
                #pragma unroll
                for (int tn = 0; tn < 4; ++tn)
                    acc[tn] = __builtin_amdgcn_mfma_f32_16x16x32_bf16(afr[kk], bfr[tn][kk], acc[tn], 0, 0, 0);
            #pragma unroll
            for (int tn = 0; tn < 4; ++tn) {
                const unsigned col = 64 * w + 16 * tn + c;
                #pragma unroll
                for (int r = 0; r < 4; ++r) {
                    const size_t row = Rj + 16 * mt + q * 4 + r;
                    xp[row * 256 + col] = (unsigned short)bf16r(acc[tn][r]);
                }
            }
        }

        // re-stage for tile j+1: barrier (reads done) -> stage -> barrier
        if (j < 3) {
            lds_barrier();
            const float* src = inp + (Rj + 64) * 256;
            #pragma unroll
            for (int ph = 0; ph < 8; ++ph) {
                const int e = ph * 2048 + tid * 8;
                floatx4 f0 = *(const floatx4*)(src + e);
                floatx4 f1 = *(const floatx4*)(src + e + 4);
                *(short8*)&abuf[(e >> 8) * 264 + (e & 255)] = pack8_pk(f0, f1);
            }
            lds_barrier();
        }
    }
}

// ---------------------------------------------------------------------------
// Kernel 2: serial recurrence. 4 blocks x 16 batches, 8 WAVES/block
// (2 waves/SIMD): wave w owns a 32-wide hidden slice (2 MFMA chains).
// BYTE-IDENTICAL to the verified 1360us version: the operand-swap variant
// regressed 22% (emergent 2-wave stagger loss); do not touch the step
// structure without a stagger mechanism.
// ---------------------------------------------------------------------------
__global__ __launch_bounds__(512, 2) void rnn_kernel(
    const float* __restrict__ W_hh,
    const unsigned short* __restrict__ xp,   // bf16 bits [SEQ][NBATCH][HIDN]
    float* __restrict__ out)                 // fp32 [SEQ*NBATCH][HIDN]
{
    __shared__ __align__(16) unsigned short hbuf[2][16 * 264];
    const int tid  = threadIdx.x;
    const int w    = tid >> 6, lane = tid & 63;   // w in [0,8)
    const int c    = lane & 15, q = lane >> 4;
    const int B0   = blockIdx.x * 16;

    // B-frags for this wave's 32 columns: n = 32w + 16*t2 + c, t2 in {0,1}
    short8 bfr[2][8];
    #pragma unroll
    for (int t2 = 0; t2 < 2; ++t2) {
        const int n = 32 * w + 16 * t2 + c;
        #pragma unroll
        for (int kk = 0; kk < 8; ++kk) {
            const float* p = W_hh + (size_t)n * 256 + kk * 32 + q * 8;
            bfr[t2][kk] = pack8(*(const floatx4*)p, *(const floatx4*)(p + 4));
        }
    }

    // h0 = 0
    for (int i = tid; i < 2 * 16 * 264; i += 512) (&hbuf[0][0])[i] = 0;
    __syncthreads();

    // per-lane flat offset into [t][b][n]: b = B0+q*4+r, n = 32w+16*t2+c
    const unsigned lofs = (unsigned)(B0 + q * 4) * 256 + 32 * w + c;
    const unsigned short* xq = xp + lofs;
    float* oq = out + lofs;

    // 2-deep xp prefetch ring; i = r*2 + t2
    unsigned xa[8], xb[8];
    #pragma unroll
    for (int i = 0; i < 8; ++i) {
        const int t2 = i & 1, r = i >> 1;
        xa[i] = xq[r * 256 + t2 * 16];
        xb[i] = xq[16384 + r * 256 + t2 * 16];
    }

    auto step = [&](int t, int sel, unsigned* xv) {
        // A-frags first (only dep: barrier) so LDS latency overlaps VALU below
        short8 afr[8];
        #pragma unroll
        for (int kk = 0; kk < 8; ++kk)
            afr[kk] = *(const short8*)&hbuf[sel][c * 264 + kk * 32 + q * 8];

        // acc init = x_proj (prefetched 2 steps ago; bf16 -> f32 is <<16)
        floatx4 acc[2];
        #pragma unroll
        for (int t2 = 0; t2 < 2; ++t2) {
            floatx4 a0;
            a0[0] = __builtin_bit_cast(float, xv[0 * 2 + t2] << 16);
            a0[1] = __builtin_bit_cast(float, xv[1 * 2 + t2] << 16);
            a0[2] = __builtin_bit_cast(float, xv[2 * 2 + t2] << 16);
            a0[3] = __builtin_bit_cast(float, xv[3 * 2 + t2] << 16);
            acc[t2] = a0;
        }

        // prefetch x_proj for t+2 (clamped; dead-but-in-bounds at the tail)
        {
            const int tp = (t + 2 < SEQ) ? (t + 2) : (SEQ - 1);
            const unsigned short* p = xq + (size_t)tp * 16384;
            #pragma unroll
            for (int i = 0; i < 8; ++i) {
                const int t2 = i & 1, r = i >> 1;
                xv[i] = p[r * 256 + t2 * 16];
            }
        }

        // kk-outer: 2 interleaved chains; second wave on the SIMD fills gaps
        #pragma unroll
        for (int kk = 0; kk < 8; ++kk)
            #pragma unroll
            for (int t2 = 0; t2 < 2; ++t2)
                acc[t2] = __builtin_amdgcn_mfma_f32_16x16x32_bf16(afr[kk], bfr[t2][kk], acc[t2], 0, 0, 0);

        // epilogue: tanh, fp32 out store, bf16 h_new into other LDS buffer
        float* op = oq + (size_t)t * 16384;
        unsigned short* hw = &hbuf[sel ^ 1][0];
        #pragma unroll
        for (int t2 = 0; t2 < 2; ++t2) {
            #pragma unroll
            for (int r = 0; r < 4; ++r) {
                const float hn = tanh_fast(acc[t2][r]);
                op[r * 256 + t2 * 16] = hn;
                hw[(q * 4 + r) * 264 + 32 * w + 16 * t2 + c] = (unsigned short)bf16r(hn);
            }
        }
        lds_barrier();
    };

    for (int t = 0; t < SEQ; t += 2) {
        step(t, 0, xa);
        step(t + 1, 1, xb);
    }
}

extern "C" void kernel_launch(void* const* d_in, const int* in_sizes, int n_in,
                              void* d_out, int out_size, void* d_ws, size_t ws_size,
                              hipStream_t stream) {
    const float* input = (const float*)d_in[0];
    const float* W_ih  = (const float*)d_in[1];
    const float* W_hh  = (const float*)d_in[2];
    const float* b_ih  = (const float*)d_in[3];
    const float* b_hh  = (const float*)d_in[4];
    float* out = (float*)d_out;
    unsigned short* xp = (unsigned short*)d_ws;  // 2048*64*256 bf16 = 64 MiB

    proj_kernel<<<512, 256, 0, stream>>>(input, W_ih, b_ih, b_hh, xp);
    rnn_kernel<<<4, 512, 0, stream>>>(W_hh, xp, out);
}